// Round 1
// baseline (87.144 us; speedup 1.0000x reference)
//
#include <hip/hip_runtime.h>
#include <math.h>

// Tropical (min-plus) matmul: out[b,o] = min_j (x[b,j] + w[o,j])
// x: [512, 512] f32, w: [1024, 512] f32, out: [512, 1024] f32
//
// R3 post-mortem: 73.6us total = ~42us harness poison fill + ~31.6us kernel.
// Kernel accounting: VALU floor 3.4us (1 inst/MAC via pk_add+min3), but the
// 2x2 thread tile reads 4 B/MAC from LDS -> 4.19 MB/CU -> 4096 b128
// wave-reads/CU x ~12cyc = 20.5us -> LDS-return-BW bound, not VALU.
// R4: 4x4 register tile halves LDS traffic to 2 B/MAC (2048 reads/CU,
// ~10.3us floor). 128 thr/block (2 waves), TB=32 x TO=64, grid 16x16 =
// 256 blocks = exactly 1/CU. Strided row ownership (x: tb+8i, w: to+16ii)
// keeps per-inst LDS addresses on distinct 4-bank groups with PADW=132
// (stride%32==4): x-reads conflict-free (16-lane bcast), w-reads 2-way
// (free per m136). Contiguous rows (4*to+i) would be 8-way-conflicted.
// Predicted kernel ~11-13us -> total ~52-56us.

typedef float v2f __attribute__((ext_vector_type(2)));

#define B_    512
#define IN_   512
#define OUT_  1024
#define TB    32     // b rows per block
#define TO    64     // o rows per block
#define BK    128
#define PADW  132    // floats per LDS row = 528B; %16==0 -> b128-aligned rows

__global__ __launch_bounds__(128) void tropical_kernel(
    const float* __restrict__ x, const float* __restrict__ w,
    float* __restrict__ out)
{
    __shared__ float xs[TB * PADW];  // 32*132*4 = 16.9 KB
    __shared__ float ws[TO * PADW];  // 64*132*4 = 33.8 KB   (total ~50 KB)

    const int tid = threadIdx.x;
    const int b0 = blockIdx.x * TB;
    const int o0 = blockIdx.y * TO;

    // staging: tile rows are 32 float4s wide; 128 threads = 4 f4-rows/pass
    const int scol  = tid & 31;   // float4 column (0..31)
    const int srow0 = tid >> 5;   // row 0..3, +4 per pass

    // compute: thread tile 4(b) x 4(o); strided row ownership
    const int to = tid & 15;      // w rows: to + 16*ii
    const int tb = tid >> 4;      // x rows: tb + 8*i   (0..7 across block)

    float acc[4][4];
#pragma unroll
    for (int i = 0; i < 4; ++i)
#pragma unroll
        for (int ii = 0; ii < 4; ++ii) acc[i][ii] = INFINITY;

    for (int k0 = 0; k0 < IN_; k0 += BK) {
        // ---- stage x tile: 32 rows x 32 f4 (8 per thread) ----
#pragma unroll
        for (int p = 0; p < 8; ++p) {
            const int r = srow0 + p * 4;
            const float4 v = *(const float4*)&x[(size_t)(b0 + r) * IN_ + k0 + scol * 4];
            *(float4*)&xs[r * PADW + scol * 4] = v;
        }
        // ---- stage w tile: 64 rows x 32 f4 (16 per thread) ----
#pragma unroll
        for (int p = 0; p < 16; ++p) {
            const int r = srow0 + p * 4;
            const float4 v = *(const float4*)&w[(size_t)(o0 + r) * IN_ + k0 + scol * 4];
            *(float4*)&ws[r * PADW + scol * 4] = v;
        }
        __syncthreads();

        // ---- main loop: per 4j, 8x ds_read_b128 + 32 pk_add + 32 min3 ----
        // 64 MACs / 8 reads = 2 B/MAC (vs 4 B/MAC at 2x2 tile)
#pragma unroll 4
        for (int j = 0; j < BK; j += 4) {
            float4 xa[4], wa[4];
#pragma unroll
            for (int i = 0; i < 4; ++i)
                xa[i] = *(const float4*)&xs[(tb + 8 * i) * PADW + j];
#pragma unroll
            for (int ii = 0; ii < 4; ++ii)
                wa[ii] = *(const float4*)&ws[(to + 16 * ii) * PADW + j];

#pragma unroll
            for (int i = 0; i < 4; ++i) {
                const v2f x0 = {xa[i].x, xa[i].y};
                const v2f x1 = {xa[i].z, xa[i].w};
#pragma unroll
                for (int ii = 0; ii < 4; ++ii) {
                    const v2f w0 = {wa[ii].x, wa[ii].y};
                    const v2f w1 = {wa[ii].z, wa[ii].w};
                    v2f t;
                    t = x0 + w0;  // v_pk_add_f32
                    acc[i][ii] = fminf(fminf(acc[i][ii], t.x), t.y);  // v_min3_f32
                    t = x1 + w1;
                    acc[i][ii] = fminf(fminf(acc[i][ii], t.x), t.y);
                }
            }
        }
        __syncthreads();
    }

    // ---- epilogue: 16 scalar stores (rows b0+tb+8i, cols o0+to+16ii) ----
    // lanes with consecutive `to` store consecutive floats -> 64B segments
#pragma unroll
    for (int i = 0; i < 4; ++i) {
#pragma unroll
        for (int ii = 0; ii < 4; ++ii) {
            out[(size_t)(b0 + tb + 8 * i) * OUT_ + o0 + to + 16 * ii] = acc[i][ii];
        }
    }
}

extern "C" void kernel_launch(void* const* d_in, const int* in_sizes, int n_in,
                              void* d_out, int out_size, void* d_ws, size_t ws_size,
                              hipStream_t stream) {
    const float* x = (const float*)d_in[0];   // [512, 512]
    const float* w = (const float*)d_in[1];   // [1024, 512]
    float* out = (float*)d_out;               // [512, 1024]

    dim3 grid(B_ / TB, OUT_ / TO);            // 16 x 16 = 256 blocks, 1/CU
    tropical_kernel<<<grid, 128, 0, stream>>>(x, w, out);
}

// Round 2
// 74.625 us; speedup vs baseline: 1.1678x; 1.1678x over previous
//
#include <hip/hip_runtime.h>
#include <math.h>

// Tropical (min-plus) matmul: out[b,o] = min_j (x[b,j] + w[o,j])
// x: [512, 512] f32, w: [1024, 512] f32, out: [512, 1024] f32
//
// R4 post-mortem: 4x4 reg tile halved LDS bytes but dropped the device to
// 2 waves/CU (2 SIMDs idle, 0 latency hiding) -> kernel ~47us (worse than
// R3's ~31.6). Lesson: keep 8 waves/CU (2/SIMD) at all costs.
// R5: split operand streams across pipes instead of growing the reg tile.
//   - o-per-lane: lane owns w row (o = o0+lane); w read from LDS once per
//     (lane,j) = 2KB/lane = 1 MB/CU total (R3 was 4.19 MB/CU).
//   - x via SMEM: wave's 4 b-rows are wave-uniform (readfirstlane) ->
//     s_load_dwordx4 through K$; zero LDS/VMEM cost on the x side.
//   - 1 inst/MAC kept: v_pk_add_f32 + v_min3_f32.
//   - staging: global_load_lds width=16 with PRE-SWIZZLED global source
//     (rule 21/m173): LDS dest linear (base + lane*16), logical col c of
//     row r lands at phys group (c ^ (r&31)). Reads use the same XOR ->
//     each ds_read_b128 hits every bank exactly 8x = contiguous-b128
//     service pattern = conflict-free. No ds_write insts at all.
//   - 512 blocks x 256 thr (4 waves share the o-slab, each wave 4 b's),
//     2 blocks/CU, 8 waves/CU, 2/SIMD == R3's proven occupancy shape.
// Budget/CU: LDS 8w*64ch*2*12cyc = 12.3k cyc (5.1us), VALU 3.4us
// (overlapped), SMEM tiny. Predict kernel ~8-12us, total ~49-55us,
// SQ_LDS_BANK_CONFLICT ~0, LDS_Block_Size 32768.

typedef float v2f __attribute__((ext_vector_type(2)));

#define B_    512
#define IN_   512
#define OUT_  1024
#define TBb   16     // b rows per block (4 waves x 4)
#define TOo   64     // o rows per block (one per lane)
#define BK    128    // K-step (4 steps total)
#define NCHUNK (BK / 8)

#define AS1 __attribute__((address_space(1)))
#define AS3 __attribute__((address_space(3)))

__global__ __launch_bounds__(256, 2) void tropical_kernel(
    const float* __restrict__ x, const float* __restrict__ w,
    float* __restrict__ out)
{
    // 64 rows x 128 floats, linear (no pad) -> global_load_lds-compatible.
    __shared__ __align__(16) float ws[TOo * BK];   // 32 KB

    const int tid  = threadIdx.x;
    const int lane = tid & 63;
    const int lswz = lane & 31;
    const int wid  = __builtin_amdgcn_readfirstlane(tid >> 6);  // wave id 0..3
    const int o0   = blockIdx.y * TOo;
    const int bblk = blockIdx.x * TBb;
    const int b0   = bblk + 4 * wid;   // this wave's 4 b-rows (wave-uniform)

    // staging coords: 256 thr = 8 rows x 32 f4-cols per pass, 8 passes
    const int c4 = tid & 31;   // f4 column 0..31
    const int r0 = tid >> 5;   // row slot 0..7

    float acc0 = INFINITY, acc1 = INFINITY, acc2 = INFINITY, acc3 = INFINITY;

    for (int k0 = 0; k0 < IN_; k0 += BK) {
        // ---- stage w[o0..o0+63][k0..k0+127] -> ws via LDS-DMA ----
        // LDS dest is linear (wave base + lane*16); the XOR swizzle is
        // applied on the GLOBAL source column, so phys slot [r][c4] holds
        // logical col group (c4 ^ (r&31)).
#pragma unroll
        for (int p = 0; p < 8; ++p) {
            const int r  = r0 + 8 * p;
            const int gc = (c4 ^ (r & 31)) * 4;              // logical float col
            const float* gsrc = &w[(size_t)(o0 + r) * IN_ + k0 + gc];
            float* ldst = &ws[r * BK + c4 * 4];
            __builtin_amdgcn_global_load_lds((const AS1 unsigned int*)gsrc,
                                             (AS3 unsigned int*)ldst, 16, 0, 0);
        }
        __syncthreads();   // drains vmcnt(0) before any wave reads ws

        const char*  wsrow = (const char*)ws + (size_t)lane * (BK * 4);
        const float* xr0 = &x[(size_t)(b0 + 0) * IN_ + k0];
        const float* xr1 = &x[(size_t)(b0 + 1) * IN_ + k0];
        const float* xr2 = &x[(size_t)(b0 + 2) * IN_ + k0];
        const float* xr3 = &x[(size_t)(b0 + 3) * IN_ + k0];

        // ---- inner: per 8-j chunk: 2 ds_read_b128 (w, swizzled) +
        //      8 uniform s_load_dwordx4 (x) + 16 pk_add + 16 min3 ----
#define STEP(xr, accv)                                                  \
        {                                                               \
            const float4 xa = *(const float4*)&xr[8 * t];               \
            const float4 xb = *(const float4*)&xr[8 * t + 4];           \
            v2f s;                                                      \
            s = (v2f){wa.x, wa.y} + (v2f){xa.x, xa.y};                  \
            accv = fminf(fminf(accv, s.x), s.y);                        \
            s = (v2f){wa.z, wa.w} + (v2f){xa.z, xa.w};                  \
            accv = fminf(fminf(accv, s.x), s.y);                        \
            s = (v2f){wb.x, wb.y} + (v2f){xb.x, xb.y};                  \
            accv = fminf(fminf(accv, s.x), s.y);                        \
            s = (v2f){wb.z, wb.w} + (v2f){xb.z, xb.w};                  \
            accv = fminf(fminf(accv, s.x), s.y);                        \
        }

#pragma unroll 2
        for (int t = 0; t < NCHUNK; ++t) {
            const float4 wa = *(const float4*)(wsrow + 16 * (((2 * t))     ^ lswz));
            const float4 wb = *(const float4*)(wsrow + 16 * (((2 * t) + 1) ^ lswz));
            STEP(xr0, acc0)
            STEP(xr1, acc1)
            STEP(xr2, acc2)
            STEP(xr3, acc3)
        }
#undef STEP
        __syncthreads();   // protect ws before next K-step's staging
    }

    // ---- epilogue: 4 coalesced stores (lane -> consecutive o) ----
    out[(size_t)(b0 + 0) * OUT_ + o0 + lane] = acc0;
    out[(size_t)(b0 + 1) * OUT_ + o0 + lane] = acc1;
    out[(size_t)(b0 + 2) * OUT_ + o0 + lane] = acc2;
    out[(size_t)(b0 + 3) * OUT_ + o0 + lane] = acc3;
}

extern "C" void kernel_launch(void* const* d_in, const int* in_sizes, int n_in,
                              void* d_out, int out_size, void* d_ws, size_t ws_size,
                              hipStream_t stream) {
    const float* x = (const float*)d_in[0];   // [512, 512]
    const float* w = (const float*)d_in[1];   // [1024, 512]
    float* out = (float*)d_out;               // [512, 1024]

    dim3 grid(B_ / TBb, OUT_ / TOo);          // 32 x 16 = 512 blocks, 2/CU
    tropical_kernel<<<grid, 256, 0, stream>>>(x, w, out);
}